// Round 21
// baseline (779.691 us; speedup 1.0000x reference)
//
#include <hip/hip_runtime.h>
#include <math.h>

constexpr int N_   = 50000;
constexpr int E_   = 800000;
constexpr int FIN_ = 32;
constexpr int D_   = 128;
constexpr int H_   = 8;
constexpr int NB_  = 5;
constexpr int L_   = 4;
constexpr int DFF_ = 512;

typedef __attribute__((ext_vector_type(8))) short short8;
typedef __attribute__((ext_vector_type(4))) short short4v;
typedef __attribute__((ext_vector_type(4))) float f32x4;
typedef __attribute__((ext_vector_type(2))) float f32x2;

__device__ __forceinline__ short f2bf(float f){
  unsigned u = __float_as_uint(f);
  unsigned r = (u + 0x7FFFu + ((u >> 16) & 1u)) >> 16;
  return (short)r;
}
__device__ __forceinline__ float bf2f(short v){
  return __uint_as_float(((unsigned)(unsigned short)v) << 16);
}
__device__ __forceinline__ float bflo(unsigned u){ return __uint_as_float(u << 16); }
__device__ __forceinline__ float bfhi(unsigned u){ return __uint_as_float(u & 0xffff0000u); }

// fp8 e4m3 encode via gfx950 HW converts (self-consistent with decode)
__device__ __forceinline__ unsigned char f2fp8(float x){
  int p = __builtin_amdgcn_cvt_pk_fp8_f32(x, x, 0, false);
  return (unsigned char)(p & 0xFF);
}

// inline exact-gelu via A&S 7.1.26 erf (|err|<1.5e-7)
__device__ __forceinline__ float gelu_f(float x){
  float xs = x * 0.70710678118654752f;
  float ax = fabsf(xs);
  float t  = __builtin_amdgcn_rcpf(1.0f + 0.3275911f*ax);
  float y  = t*(0.254829592f + t*(-0.284496736f + t*(1.421413741f +
             t*(-1.453152027f + t*1.061405429f))));
  float e  = exp2f(-ax*ax*1.4426950408889634f);
  float er = 1.0f - y*e;
  er = __uint_as_float((__float_as_uint(er) & 0x7fffffffu) |
                       (__float_as_uint(xs) & 0x80000000u));
  return 0.5f*x*(1.0f + er);
}

// packed-fragment weight index: wave B-frag load = ONE coalesced 1KB read
__device__ __forceinline__ size_t pfidx(int n, int k, int K){
  return ((size_t)(n >> 4)*(2*K) + (size_t)(k >> 3)*16 + (n & 15))*8 + (k & 7);
}

// ---------------- weight convert + transpose to packed bf16 (once per call) ----------------
__global__ __launch_bounds__(256)
void conv_weights(const float* __restrict__ Wq, const float* __restrict__ Wk,
                  const float* __restrict__ Wv, const float* __restrict__ Wo,
                  const float* __restrict__ w1, const float* __restrict__ w2,
                  const float* __restrict__ ow,
                  short* __restrict__ wqkvt, short* __restrict__ wot,
                  short* __restrict__ w1t, short* __restrict__ w2t,
                  short* __restrict__ owt){
  int idx = blockIdx.x * blockDim.x + threadIdx.x;
  if (idx < 3*L_*16384){
    int m = idx / (L_*16384);
    int r = idx % (L_*16384);
    int l = r / 16384, e = r % 16384;
    int k = e >> 7, n = e & 127;
    const float* src = (m == 0) ? Wq : ((m == 1) ? Wk : Wv);
    wqkvt[(size_t)(l*3 + m)*16384 + pfidx(n, k, 128)] = f2bf(src[(size_t)l*16384 + e]);
    return;
  }
  idx -= 3*L_*16384;
  if (idx < L_*16384){
    int l = idx / 16384, e = idx % 16384, k = e >> 7, n = e & 127;
    wot[(size_t)l*16384 + pfidx(n, k, 128)] = f2bf(Wo[idx]);
    return;
  }
  idx -= L_*16384;
  if (idx < L_*D_*DFF_){            // w1: K=128 N=512
    int l = idx / 65536, e = idx % 65536;
    int k = e >> 9, n = e & 511;
    w1t[(size_t)l*65536 + pfidx(n, k, 128)] = f2bf(w1[idx]);
    return;
  }
  idx -= L_*D_*DFF_;
  if (idx < L_*DFF_*D_){            // w2: K=512 N=128
    int l = idx / 65536, e = idx % 65536;
    int k = e >> 7, n = e & 127;
    w2t[(size_t)l*65536 + pfidx(n, k, 512)] = f2bf(w2[idx]);
    return;
  }
  idx -= L_*DFF_*D_;
  if (idx < 16384){
    int k = idx >> 7, n = idx & 127;
    owt[pfidx(n, k, 128)] = f2bf(ow[idx]);
  }
}

// ---------------- input projection (2 nodes / block) ----------------
__global__ __launch_bounds__(256)
void input_proj(const float* __restrict__ x, const float* __restrict__ in_w,
                const float* __restrict__ in_b, const float* __restrict__ se,
                const int* __restrict__ sid, short* __restrict__ hb){
  int sub = threadIdx.x >> 7, d = threadIdx.x & 127;
  int i = blockIdx.x*2 + sub;
  __shared__ float xs[2][FIN_];
  if (d < FIN_) xs[sub][d] = x[(size_t)i*FIN_ + d];
  __syncthreads();
  float acc = in_b[d] + se[(size_t)sid[i]*D_ + d];
  #pragma unroll 8
  for (int k=0;k<FIN_;k++) acc += xs[sub][k]*in_w[k*D_+d];
  hb[(size_t)i*D_+d] = f2bf(acc);
}

// ---------------- CSR build ----------------
__global__ void k_deg(const int* __restrict__ dst, const int* __restrict__ src,
                      const int* __restrict__ band,
                      int* __restrict__ deg, int* __restrict__ pk){
  int e = blockIdx.x*blockDim.x + threadIdx.x;
  if (e < E_){
    atomicAdd(&deg[dst[e]], 1);
    pk[e] = src[e] | (band[e] << 16);
  }
}

__global__ __launch_bounds__(1024)
void k_scan1(const int* __restrict__ deg, int* __restrict__ rowptr,
             int* __restrict__ bsum){
  __shared__ int sm[1024];
  int b = blockIdx.x, tid = threadIdx.x;
  int i = b*1024 + tid;
  int v = (i < N_) ? deg[i] : 0;
  sm[tid] = v; __syncthreads();
  for (int off=1; off<1024; off<<=1){
    int t = (tid>=off) ? sm[tid-off] : 0;
    __syncthreads();
    sm[tid] += t;
    __syncthreads();
  }
  if (i < N_) rowptr[i+1] = sm[tid];
  if (tid == 1023) bsum[b] = sm[1023];
}

__global__ void k_scan2(int* __restrict__ bsum, int nb){
  int tid = threadIdx.x;
  int v = (tid < nb) ? bsum[tid] : 0;
  for (int off=1; off<64; off<<=1){
    int t = __shfl_up(v, off, 64);
    if (tid >= off) v += t;
  }
  if (tid < nb) bsum[tid] = v;
}

__global__ void k_scan3(int* __restrict__ rowptr, const int* __restrict__ bsum){
  int i = blockIdx.x*blockDim.x + threadIdx.x;
  if (i == 0) rowptr[0] = 0;
  if (i < N_){
    int b = i >> 10;
    if (b > 0) rowptr[i+1] += bsum[b-1];
  }
}

__global__ void k_scatter(const int* __restrict__ dst, const int* __restrict__ rowptr,
                          int* __restrict__ fill, int* __restrict__ eord){
  int e = blockIdx.x*blockDim.x + threadIdx.x;
  if (e < E_){
    int d = dst[e];
    int pos = rowptr[d] + atomicAdd(&fill[d], 1);
    eord[pos] = e;
  }
}

__global__ void k_sortseg(const int* __restrict__ rowptr, int* __restrict__ eord){
  int i = blockIdx.x*blockDim.x + threadIdx.x;
  if (i >= N_) return;
  int b = rowptr[i], t = rowptr[i+1];
  for (int p = b+1; p < t; p++){
    int v = eord[p];
    int q = p-1;
    while (q >= b && eord[q] > v){ eord[q+1] = eord[q]; q--; }
    eord[q+1] = v;
  }
}

// CSR-ordered edge meta: em[p] = (src|band<<16, eattr bits)
__global__ void k_emeta(const int* __restrict__ eord, const int* __restrict__ pk,
                        const float* __restrict__ eattr, int2* __restrict__ em){
  int p = blockIdx.x*blockDim.x + threadIdx.x;
  if (p < E_){
    int e = eord[p];
    em[p] = make_int2(pk[e], __float_as_int(eattr[e]));
  }
}

// ---------------- direct-global bf16 MFMA GEMM: C = A(Mx128) @ W(128x128) ----------------
// BM=128, 512 threads = 8 waves, wave tile 64x32 (acc[4][2]). W packed-fragment.
// EPI: 3 = bias -> f32 | 4 = QKV: by0 -> Q bf16 ld128; by1/2 -> K/V fp8 into [N][256B]
template<int EPI>
__global__ __launch_bounds__(512, 2)
void gemm128_direct(const short* __restrict__ A, const short* __restrict__ Wt,
                    const float* __restrict__ bias,
                    float* Cf, short* Yb, unsigned char* KV8, int M, long wstride){
  const int tid = threadIdx.x;
  const int by  = blockIdx.y;
  Wt += (size_t)by * wstride;
  const short8* W8 = (const short8*)Wt;
  const int m0 = blockIdx.x * 128;
  const int lane = tid & 63, w = tid >> 6;
  const int wr = w >> 2, wc = w & 3;
  const int lrow = lane & 15, lgrp = lane >> 4;
  f32x4 acc[4][2];
  #pragma unroll
  for (int r=0;r<4;r++){ acc[r][0] = {0.f,0.f,0.f,0.f}; acc[r][1] = {0.f,0.f,0.f,0.f}; }
  int rowA[4];
  #pragma unroll
  for (int r=0;r<4;r++){
    int rr = m0 + wr*64 + r*16 + lrow;
    rowA[r] = (rr < M) ? rr : (M-1);
  }
  #pragma unroll
  for (int kk = 0; kk < 4; kk++){
    const int koff = kk*32 + lgrp*8;
    short8 af[4], bfr[2];
    #pragma unroll
    for (int r = 0; r < 4; r++)
      af[r] = *(const short8*)(A + (size_t)rowA[r]*128 + koff);
    #pragma unroll
    for (int c = 0; c < 2; c++)
      bfr[c] = W8[(size_t)(wc*2 + c)*256 + kk*64 + lane];
    #pragma unroll
    for (int r = 0; r < 4; r++)
      #pragma unroll
      for (int c = 0; c < 2; c++)
        acc[r][c] = __builtin_amdgcn_mfma_f32_16x16x32_bf16(af[r], bfr[c], acc[r][c], 0, 0, 0);
  }
  #pragma unroll
  for (int r = 0; r < 4; r++){
    #pragma unroll
    for (int c = 0; c < 2; c++){
      int col = wc*32 + c*16 + lrow;
      float bv = (EPI == 3) ? bias[col] : 0.f;
      #pragma unroll
      for (int v = 0; v < 4; v++){
        int row = m0 + wr*64 + r*16 + lgrp*4 + v;
        if (row < M){
          float o = acc[r][c][v] + bv;
          if (EPI == 3) Cf[(size_t)row*128 + col] = o;
          else if (by == 0) Yb[(size_t)row*128 + col] = f2bf(o);
          else KV8[(size_t)row*256 + (by-1)*128 + col] = f2fp8(o);
        }
      }
    }
  }
}

// ---------------- FUSED layer tail (BM=32, 4 waves, (256,8)): ----------------
// hb = LN2( FFN(LN1(aggb@Wo + b + hb)) + LN1out )
// Phase A: Wo GEMM + bf16 residual + register-LN1 -> y bf16 -> ytile (8KB).
// Phase B: 4-chunk FFN; A-frags from ytile; hidden single-buffer (8KB).
// Phase C: register-LN2 (residual from ytile) -> hb. LDS ~17.4KB -> 8 blocks/CU.
__global__ __launch_bounds__(256, 8)
void wo_ffn_fused(const short* __restrict__ aggb, const short* __restrict__ wot,
                  const float* __restrict__ wo_b, short* __restrict__ hb,
                  const short* __restrict__ w1t, const float* __restrict__ b1,
                  const short* __restrict__ w2t, const float* __restrict__ b2,
                  const float* __restrict__ g1, const float* __restrict__ bl1,
                  const float* __restrict__ g2, const float* __restrict__ bl2,
                  int M){
  __shared__ char ytile[8192];
  __shared__ char hidb[8192];
  __shared__ float rsum[4][32];
  __shared__ float rsq[4][32];
  const int tid = threadIdx.x;
  const int m0 = blockIdx.x * 32;
  const int lane = tid & 63, w = tid >> 6;     // w in 0..3 (col-wave)
  const int lrow = lane & 15, lgrp = lane >> 4;
  int rowA[2];
  #pragma unroll
  for (int r=0;r<2;r++){
    int rr = m0 + r*16 + lrow;
    rowA[r] = (rr < M) ? rr : (M-1);
  }

  // ---------- Phase A: Wo GEMM + residual + LN1 -> ytile ----------
  {
    const short8* W8 = (const short8*)wot;
    f32x4 acc[2][2];
    #pragma unroll
    for (int r=0;r<2;r++){ acc[r][0] = {0.f,0.f,0.f,0.f}; acc[r][1] = {0.f,0.f,0.f,0.f}; }
    #pragma unroll
    for (int kk = 0; kk < 4; kk++){
      const int koff = kk*32 + lgrp*8;
      short8 af[2], bfr[2];
      #pragma unroll
      for (int r = 0; r < 2; r++)
        af[r] = *(const short8*)(aggb + (size_t)rowA[r]*128 + koff);
      #pragma unroll
      for (int c = 0; c < 2; c++)
        bfr[c] = W8[(size_t)(w*2 + c)*256 + kk*64 + lane];
      #pragma unroll
      for (int r = 0; r < 2; r++)
        #pragma unroll
        for (int c = 0; c < 2; c++)
          acc[r][c] = __builtin_amdgcn_mfma_f32_16x16x32_bf16(af[r], bfr[c], acc[r][c], 0, 0, 0);
    }
    float o[2][2][4];
    float ps[2][4], pq[2][4];
    #pragma unroll
    for (int r=0;r<2;r++)
      #pragma unroll
      for (int v=0;v<4;v++){ ps[r][v]=0.f; pq[r][v]=0.f; }
    #pragma unroll
    for (int r = 0; r < 2; r++){
      #pragma unroll
      for (int c = 0; c < 2; c++){
        int col = w*32 + c*16 + lrow;
        float bv = wo_b[col];
        #pragma unroll
        for (int v = 0; v < 4; v++){
          int grow = m0 + r*16 + lgrp*4 + v;
          int gr = (grow < M) ? grow : (M-1);
          float oo = acc[r][c][v] + bv + bf2f(hb[(size_t)gr*128 + col]);
          o[r][c][v] = oo;
          ps[r][v] += oo;
          pq[r][v] += oo*oo;
        }
      }
    }
    #pragma unroll
    for (int r = 0; r < 2; r++)
      #pragma unroll
      for (int v = 0; v < 4; v++){
        #pragma unroll
        for (int off = 1; off < 16; off <<= 1){
          ps[r][v] += __shfl_xor(ps[r][v], off, 16);
          pq[r][v] += __shfl_xor(pq[r][v], off, 16);
        }
      }
    if (lrow == 0){
      #pragma unroll
      for (int r = 0; r < 2; r++)
        #pragma unroll
        for (int v = 0; v < 4; v++){
          int row = r*16 + lgrp*4 + v;
          rsum[w][row] = ps[r][v];
          rsq[w][row]  = pq[r][v];
        }
    }
    __syncthreads();                         // stats ready
    #pragma unroll
    for (int r = 0; r < 2; r++){
      float gv[2], bv2[2];
      #pragma unroll
      for (int c = 0; c < 2; c++){
        int col = w*32 + c*16 + lrow;
        gv[c] = g1[col]; bv2[c] = bl1[col];
      }
      #pragma unroll
      for (int v = 0; v < 4; v++){
        int row = r*16 + lgrp*4 + v;
        float s = (rsum[0][row]+rsum[1][row]) + (rsum[2][row]+rsum[3][row]);
        float q = (rsq[0][row]+rsq[1][row]) + (rsq[2][row]+rsq[3][row]);
        float mean = s * (1.f/128.f);
        float var  = q * (1.f/128.f) - mean*mean;
        float rstd = rsqrtf(var + 1e-5f);
        #pragma unroll
        for (int c = 0; c < 2; c++){
          int col = w*32 + c*16 + lrow;
          float y = (o[r][c][v] - mean)*rstd*gv[c] + bv2[c];
          int off = row*256 + col*2;
          *(short*)(ytile + (off ^ ((row & 7) << 4))) = f2bf(y);
        }
      }
    }
  }
  __syncthreads();                           // ytile ready

  // ---------- Phase B: FFN over 4 chunks of 128 hidden cols ----------
  const short8* W18 = (const short8*)w1t;
  const short8* W28 = (const short8*)w2t;
  f32x4 acc2[2][2];
  #pragma unroll
  for (int r=0;r<2;r++){ acc2[r][0] = {0.f,0.f,0.f,0.f}; acc2[r][1] = {0.f,0.f,0.f,0.f}; }
  #pragma unroll
  for (int chunk = 0; chunk < 4; chunk++){
    f32x4 acc1[2][2];
    #pragma unroll
    for (int r=0;r<2;r++){ acc1[r][0] = {0.f,0.f,0.f,0.f}; acc1[r][1] = {0.f,0.f,0.f,0.f}; }
    #pragma unroll
    for (int kk = 0; kk < 4; kk++){
      const int kbyt = kk*64 + lgrp*16;
      short8 af[2], bfr[2];
      #pragma unroll
      for (int r = 0; r < 2; r++){
        int row = r*16 + lrow;                 // local row 0..31
        af[r] = *(const short8*)(ytile + ((row*256 + kbyt) ^ ((row & 7) << 4)));
      }
      #pragma unroll
      for (int c = 0; c < 2; c++){
        int nb = chunk*8 + w*2 + c;            // n1/16
        bfr[c] = W18[(size_t)nb*256 + kk*64 + lane];
      }
      #pragma unroll
      for (int r = 0; r < 2; r++)
        #pragma unroll
        for (int c = 0; c < 2; c++)
          acc1[r][c] = __builtin_amdgcn_mfma_f32_16x16x32_bf16(af[r], bfr[c], acc1[r][c], 0, 0, 0);
    }
    __syncthreads();                     // prev chunk's FFN2 hidden reads done
    #pragma unroll
    for (int r = 0; r < 2; r++){
      #pragma unroll
      for (int c = 0; c < 2; c++){
        int lc = w*32 + c*16 + lrow;           // chunk-local col
        float bv = b1[chunk*128 + lc];
        #pragma unroll
        for (int v = 0; v < 4; v++){
          int row = r*16 + lgrp*4 + v;
          float g = gelu_f(acc1[r][c][v] + bv);
          int off = row*256 + lc*2;
          *(short*)(hidb + (off ^ ((row & 7) << 4))) = f2bf(g);
        }
      }
    }
    __syncthreads();                     // hidden ready
    #pragma unroll
    for (int kk2 = 0; kk2 < 4; kk2++){
      short8 ah[2], bh[2];
      #pragma unroll
      for (int r = 0; r < 2; r++){
        int row = r*16 + lrow;
        ah[r] = *(const short8*)(hidb + ((row*256 + kk2*64 + lgrp*16) ^ ((row & 7) << 4)));
      }
      #pragma unroll
      for (int c = 0; c < 2; c++){
        int nb = w*2 + c;                      // n2/16
        bh[c] = W28[(size_t)nb*1024 + chunk*256 + kk2*64 + lane];
      }
      #pragma unroll
      for (int r = 0; r < 2; r++)
        #pragma unroll
        for (int c = 0; c < 2; c++)
          acc2[r][c] = __builtin_amdgcn_mfma_f32_16x16x32_bf16(ah[r], bh[c], acc2[r][c], 0, 0, 0);
    }
  }

  // ---------- Phase C: LN2 (residual = ytile) -> hb ----------
  {
    float o2[2][2][4];
    float ps[2][4], pq[2][4];
    #pragma unroll
    for (int r=0;r<2;r++)
      #pragma unroll
      for (int v=0;v<4;v++){ ps[r][v]=0.f; pq[r][v]=0.f; }
    #pragma unroll
    for (int r = 0; r < 2; r++){
      #pragma unroll
      for (int c = 0; c < 2; c++){
        int col = w*32 + c*16 + lrow;
        float bv = b2[col];
        #pragma unroll
        for (int v = 0; v < 4; v++){
          int row = r*16 + lgrp*4 + v;
          int off = row*256 + col*2;
          float res = bf2f(*(const short*)(ytile + (off ^ ((row & 7) << 4))));
          float oo = acc2[r][c][v] + bv + res;
          o2[r][c][v] = oo;
          ps[r][v] += oo;
          pq[r][v] += oo*oo;
        }
      }
    }
    #pragma unroll
    for (int r = 0; r < 2; r++)
      #pragma unroll
      for (int v = 0; v < 4; v++){
        #pragma unroll
        for (int off = 1; off < 16; off <<= 1){
          ps[r][v] += __shfl_xor(ps[r][v], off, 16);
          pq[r][v] += __shfl_xor(pq[r][v], off, 16);
        }
      }
    __syncthreads();                         // guard rsum reuse
    if (lrow == 0){
      #pragma unroll
      for (int r = 0; r < 2; r++)
        #pragma unroll
        for (int v = 0; v < 4; v++){
          int row = r*16 + lgrp*4 + v;
          rsum[w][row] = ps[r][v];
          rsq[w][row]  = pq[r][v];
        }
    }
    __syncthreads();
    #pragma unroll
    for (int r = 0; r < 2; r++){
      float gv[2], bv2[2];
      #pragma unroll
      for (int c = 0; c < 2; c++){
        int col = w*32 + c*16 + lrow;
        gv[c] = g2[col]; bv2[c] = bl2[col];
      }
      #pragma unroll
      for (int v = 0; v < 4; v++){
        int row = r*16 + lgrp*4 + v;
        int grow = m0 + row;
        float s = (rsum[0][row]+rsum[1][row]) + (rsum[2][row]+rsum[3][row]);
        float q = (rsq[0][row]+rsq[1][row]) + (rsq[2][row]+rsq[3][row]);
        float mean = s * (1.f/128.f);
        float var  = q * (1.f/128.f) - mean*mean;
        float rstd = rsqrtf(var + 1e-5f);
        if (grow < M){
          #pragma unroll
          for (int c = 0; c < 2; c++){
            int col = w*32 + c*16 + lrow;
            float y = (o2[r][c][v] - mean)*rstd*gv[c] + bv2[c];
            hb[(size_t)grow*128 + col] = f2bf(y);
          }
        }
      }
    }
  }
}

// ---------------- fused per-node attention: 4 chains, (256,8), fp8 K/V, CSR meta ------
__global__ __launch_bounds__(256, 8)
void attn_fused(const short* __restrict__ Qb, const unsigned char* __restrict__ KV8,
                const int2* __restrict__ em,
                const int* __restrict__ rowptr,
                const float* __restrict__ bb_l, short* __restrict__ aggb){
  const int lane = threadIdx.x & 63;
  const int i = (blockIdx.x << 2) + (threadIdx.x >> 6);
  if (i >= N_) return;
  const int hh = lane >> 3;
  const unsigned qw = ((const unsigned*)Qb)[(size_t)i*64 + lane];
  const float q0 = bflo(qw), q1 = bfhi(qw);
  const int p0 = __builtin_amdgcn_readfirstlane(rowptr[i]);
  const int p1 = __builtin_amdgcn_readfirstlane(rowptr[i+1]);
  constexpr float L2E = 1.442695040888963f;
  float2 outv = {0.f, 0.f};
  if (p0 < p1){
    float s[4]; float2 acc[4];
    #pragma unroll
    for (int c=0;c<4;c++){ s[c]=0.f; acc[c].x=0.f; acc[c].y=0.f; }
    int sj[4], sjN[4];
    float bb[4], ea[4], bbN[4], eaN[4];
    int kw[4], vw[4], kwN[4], vwN[4];

    auto ldmeta = [&](int gb, int* SJ, float* BB, float* EA){
      #pragma unroll
      for (int c = 0; c < 4; c++){
        int idx = gb + c; idx = (idx < p1) ? idx : (p1 - 1);
        int2 m = em[idx];
        unsigned u = (unsigned)__builtin_amdgcn_readfirstlane(m.x);
        SJ[c] = (int)(u & 0xFFFFu);
        BB[c] = bb_l[(u >> 16)*H_ + hh];
        EA[c] = __uint_as_float((unsigned)__builtin_amdgcn_readfirstlane(m.y));
      }
    };

    ldmeta(p0, sj, bb, ea);
    #pragma unroll
    for (int c = 0; c < 4; c++){
      kw[c] = *(const unsigned short*)(KV8 + (size_t)sj[c]*256 + lane*2);
      vw[c] = *(const unsigned short*)(KV8 + (size_t)sj[c]*256 + 128 + lane*2);
    }
    ldmeta(p0 + 4, sjN, bbN, eaN);

    for (int base = p0; base < p1; base += 4){
      #pragma unroll
      for (int c = 0; c < 4; c++){
        kwN[c] = *(const unsigned short*)(KV8 + (size_t)sjN[c]*256 + lane*2);
        vwN[c] = *(const unsigned short*)(KV8 + (size_t)sjN[c]*256 + 128 + lane*2);
      }
      int sj2[4]; float bb2[4], ea2[4];
      ldmeta(base + 8, sj2, bb2, ea2);
      #pragma unroll
      for (int c = 0; c < 4; c++){
        f32x2 kf = __builtin_amdgcn_cvt_pk_f32_fp8(kw[c], false);
        float dot = q0*kf[0] + q1*kf[1];
        dot += __shfl_xor(dot, 1, 8);
        dot += __shfl_xor(dot, 2, 8);
        dot += __shfl_xor(dot, 4, 8);
        float logit = (dot*0.25f + bb[c]) * ea[c];
        logit = fminf(logit, 60.f);
        if (base + c >= p1) logit = -1.0e30f;   // tail slot -> weight 0
        float wgt = exp2f(logit * L2E);
        f32x2 vf = __builtin_amdgcn_cvt_pk_f32_fp8(vw[c], false);
        s[c]     += wgt;
        acc[c].x += wgt*vf[0];
        acc[c].y += wgt*vf[1];
      }
      #pragma unroll
      for (int c = 0; c < 4; c++){
        kw[c]=kwN[c]; vw[c]=vwN[c];
        sj[c]=sjN[c]; bb[c]=bbN[c]; ea[c]=eaN[c];
        sjN[c]=sj2[c]; bbN[c]=bb2[c]; eaN[c]=ea2[c];
      }
    }
    float S = (s[0]+s[1]) + (s[2]+s[3]);
    float Ax = (acc[0].x+acc[1].x) + (acc[2].x+acc[3].x);
    float Ay = (acc[0].y+acc[1].y) + (acc[2].y+acc[3].y);
    float inv = 1.0f / (S + 1e-16f);
    outv.x = Ax * inv;
    outv.y = Ay * inv;
  }
  unsigned lo = (unsigned)(unsigned short)f2bf(outv.x);
  unsigned hi = (unsigned)(unsigned short)f2bf(outv.y);
  ((unsigned*)aggb)[(size_t)i*64 + lane] = lo | (hi << 16);
}

extern "C" void kernel_launch(void* const* d_in, const int* in_sizes, int n_in,
                              void* d_out, int out_size, void* d_ws, size_t ws_size,
                              hipStream_t stream) {
  const float* x         = (const float*)d_in[0];
  const int*   edge_index= (const int*)  d_in[1];
  const float* edge_attr = (const float*)d_in[2];
  const int*   band_ids  = (const int*)  d_in[3];
  const int*   stage_ids = (const int*)  d_in[4];
  const float* stage_emb = (const float*)d_in[5];
  const float* in_w      = (const float*)d_in[6];
  const float* in_b      = (const float*)d_in[7];
  const float* Wq        = (const float*)d_in[8];
  const float* Wk        = (const float*)d_in[9];
  const float* Wv        = (const float*)d_in[10];
  const float* Wo        = (const float*)d_in[11];
  const float* Wo_b      = (const float*)d_in[12];
  const float* band_bias = (const float*)d_in[13];
  const float* ln1_g     = (const float*)d_in[14];
  const float* ln1_b     = (const float*)d_in[15];
  const float* ffn_w1    = (const float*)d_in[16];
  const float* ffn_b1    = (const float*)d_in[17];
  const float* ffn_w2    = (const float*)d_in[18];
  const float* ffn_b2    = (const float*)d_in[19];
  const float* ln2_g     = (const float*)d_in[20];
  const float* ln2_b     = (const float*)d_in[21];
  const float* out_w     = (const float*)d_in[22];
  const float* out_b     = (const float*)d_in[23];
  float* out = (float*)d_out;

  const size_t ND = (size_t)N_*D_;           // 6.4M
  float* ws  = (float*)d_ws;
  short* hb   = (short*)ws;                  // bf16 N x 128 (ONLY hidden state)
  short* aggb = (short*)(ws + ND);           // bf16 N x 128
  short* qb   = (short*)(ws + 2*ND);         // bf16 Q N x 128
  unsigned char* kv8 = (unsigned char*)(ws + 2*ND + ND/2);  // fp8 KV [N][256B]
  short* wbuf = (short*)(ws + 3*ND + ND/2);  // packed bf16 weights: 802816 shorts
  short* wqkvt = wbuf;
  short* wot   = wbuf + 196608;
  short* w1t   = wbuf + 262144;
  short* w2t   = wbuf + 524288;
  short* owt   = wbuf + 786432;
  int*  ibase = (int*)(ws + 3*ND + ND/2 + 401408);
  int*  deg   = ibase;                       // N
  int*  fill  = ibase + N_;                  // N
  int*  rowptr= ibase + 2*N_;                // N+1
  int*  eord  = ibase + 3*N_ + 1;            // E
  int*  bsum  = ibase + 3*N_ + 1 + E_;       // 64
  int*  pk    = ibase + 3*N_ + 1 + E_ + 64;  // E
  int2* em    = (int2*)(ibase + 3*N_ + 1 + 2*E_ + 64);  // E int2

  const int* srcA = edge_index;
  const int* dstA = edge_index + E_;

  hipMemsetAsync(deg, 0, 2ull*N_*sizeof(int), stream);

  conv_weights<<<3136, 256, 0, stream>>>(Wq, Wk, Wv, Wo, ffn_w1, ffn_w2, out_w,
                                         wqkvt, wot, w1t, w2t, owt);
  input_proj<<<N_/2, 256, 0, stream>>>(x, in_w, in_b, stage_emb, stage_ids, hb);

  k_deg   <<<(E_+255)/256, 256, 0, stream>>>(dstA, srcA, band_ids, deg, pk);
  k_scan1 <<<49, 1024, 0, stream>>>(deg, rowptr, bsum);
  k_scan2 <<<1, 64, 0, stream>>>(bsum, 49);
  k_scan3 <<<(N_+255)/256, 256, 0, stream>>>(rowptr, bsum);
  k_scatter<<<(E_+255)/256, 256, 0, stream>>>(dstA, rowptr, fill, eord);
  k_sortseg<<<(N_+255)/256, 256, 0, stream>>>(rowptr, eord);
  k_emeta <<<(E_+255)/256, 256, 0, stream>>>(eord, pk, edge_attr, em);

  const int GB  = (N_ + 127) / 128;          // 391
  const int GB3 = (N_ + 31) / 32;            // 1563
  const int AB  = (N_ + 3) / 4;              // 12500

  for (int l = 0; l < L_; l++){
    // Q (bf16 ld128) + K/V (fp8 interleaved [N][256B]) from hb
    gemm128_direct<4><<<dim3(GB,3), 512, 0, stream>>>(
        hb, wqkvt + (size_t)l*3*16384, nullptr, nullptr, qb, kv8, N_, 16384L);

    attn_fused<<<AB, 256, 0, stream>>>(qb, kv8, em, rowptr,
                                       band_bias + l*NB_*H_, aggb);

    // hb = LN2( FFN(LN1(aggb@Wo + b + hb)) + LN1out )   — one fused kernel, BM=32
    wo_ffn_fused<<<GB3, 256, 0, stream>>>(
        aggb, wot + (size_t)l*16384, Wo_b + l*D_, hb,
        w1t + (size_t)l*65536, ffn_b1 + l*DFF_,
        w2t + (size_t)l*65536, ffn_b2 + l*D_,
        ln1_g + l*D_, ln1_b + l*D_, ln2_g + l*D_, ln2_b + l*D_, N_);
  }

  gemm128_direct<3><<<GB, 512, 0, stream>>>(
      hb, owt, out_b, out, nullptr, nullptr, N_, 0L);
}

// Round 22
// 699.866 us; speedup vs baseline: 1.1141x; 1.1141x over previous
//
#include <hip/hip_runtime.h>
#include <math.h>

constexpr int N_   = 50000;
constexpr int E_   = 800000;
constexpr int FIN_ = 32;
constexpr int D_   = 128;
constexpr int H_   = 8;
constexpr int NB_  = 5;
constexpr int L_   = 4;
constexpr int DFF_ = 512;

typedef __attribute__((ext_vector_type(8))) short short8;
typedef __attribute__((ext_vector_type(4))) short short4v;
typedef __attribute__((ext_vector_type(4))) float f32x4;
typedef __attribute__((ext_vector_type(2))) float f32x2;

__device__ __forceinline__ short f2bf(float f){
  unsigned u = __float_as_uint(f);
  unsigned r = (u + 0x7FFFu + ((u >> 16) & 1u)) >> 16;
  return (short)r;
}
__device__ __forceinline__ float bf2f(short v){
  return __uint_as_float(((unsigned)(unsigned short)v) << 16);
}
__device__ __forceinline__ float bflo(unsigned u){ return __uint_as_float(u << 16); }
__device__ __forceinline__ float bfhi(unsigned u){ return __uint_as_float(u & 0xffff0000u); }

// fp8 e4m3 encode via gfx950 HW converts (self-consistent with decode)
__device__ __forceinline__ unsigned char f2fp8(float x){
  int p = __builtin_amdgcn_cvt_pk_fp8_f32(x, x, 0, false);
  return (unsigned char)(p & 0xFF);
}

// inline exact-gelu via A&S 7.1.26 erf (|err|<1.5e-7)
__device__ __forceinline__ float gelu_f(float x){
  float xs = x * 0.70710678118654752f;
  float ax = fabsf(xs);
  float t  = __builtin_amdgcn_rcpf(1.0f + 0.3275911f*ax);
  float y  = t*(0.254829592f + t*(-0.284496736f + t*(1.421413741f +
             t*(-1.453152027f + t*1.061405429f))));
  float e  = exp2f(-ax*ax*1.4426950408889634f);
  float er = 1.0f - y*e;
  er = __uint_as_float((__float_as_uint(er) & 0x7fffffffu) |
                       (__float_as_uint(xs) & 0x80000000u));
  return 0.5f*x*(1.0f + er);
}

// packed-fragment weight index: wave B-frag load = ONE coalesced 1KB read
__device__ __forceinline__ size_t pfidx(int n, int k, int K){
  return ((size_t)(n >> 4)*(2*K) + (size_t)(k >> 3)*16 + (n & 15))*8 + (k & 7);
}

// ---------------- weight convert + transpose to packed bf16 (once per call) ----------------
__global__ __launch_bounds__(256)
void conv_weights(const float* __restrict__ Wq, const float* __restrict__ Wk,
                  const float* __restrict__ Wv, const float* __restrict__ Wo,
                  const float* __restrict__ w1, const float* __restrict__ w2,
                  const float* __restrict__ ow,
                  short* __restrict__ wqkvt, short* __restrict__ wot,
                  short* __restrict__ w1t, short* __restrict__ w2t,
                  short* __restrict__ owt){
  int idx = blockIdx.x * blockDim.x + threadIdx.x;
  if (idx < 3*L_*16384){
    int m = idx / (L_*16384);
    int r = idx % (L_*16384);
    int l = r / 16384, e = r % 16384;
    int k = e >> 7, n = e & 127;
    const float* src = (m == 0) ? Wq : ((m == 1) ? Wk : Wv);
    wqkvt[(size_t)(l*3 + m)*16384 + pfidx(n, k, 128)] = f2bf(src[(size_t)l*16384 + e]);
    return;
  }
  idx -= 3*L_*16384;
  if (idx < L_*16384){
    int l = idx / 16384, e = idx % 16384, k = e >> 7, n = e & 127;
    wot[(size_t)l*16384 + pfidx(n, k, 128)] = f2bf(Wo[idx]);
    return;
  }
  idx -= L_*16384;
  if (idx < L_*D_*DFF_){            // w1: K=128 N=512
    int l = idx / 65536, e = idx % 65536;
    int k = e >> 9, n = e & 511;
    w1t[(size_t)l*65536 + pfidx(n, k, 128)] = f2bf(w1[idx]);
    return;
  }
  idx -= L_*D_*DFF_;
  if (idx < L_*DFF_*D_){            // w2: K=512 N=128
    int l = idx / 65536, e = idx % 65536;
    int k = e >> 7, n = e & 127;
    w2t[(size_t)l*65536 + pfidx(n, k, 512)] = f2bf(w2[idx]);
    return;
  }
  idx -= L_*DFF_*D_;
  if (idx < 16384){
    int k = idx >> 7, n = idx & 127;
    owt[pfidx(n, k, 128)] = f2bf(ow[idx]);
  }
}

// ---------------- input projection (2 nodes / block) ----------------
__global__ __launch_bounds__(256)
void input_proj(const float* __restrict__ x, const float* __restrict__ in_w,
                const float* __restrict__ in_b, const float* __restrict__ se,
                const int* __restrict__ sid, short* __restrict__ hb){
  int sub = threadIdx.x >> 7, d = threadIdx.x & 127;
  int i = blockIdx.x*2 + sub;
  __shared__ float xs[2][FIN_];
  if (d < FIN_) xs[sub][d] = x[(size_t)i*FIN_ + d];
  __syncthreads();
  float acc = in_b[d] + se[(size_t)sid[i]*D_ + d];
  #pragma unroll 8
  for (int k=0;k<FIN_;k++) acc += xs[sub][k]*in_w[k*D_+d];
  hb[(size_t)i*D_+d] = f2bf(acc);
}

// ---------------- CSR build ----------------
__global__ void k_deg(const int* __restrict__ dst, const int* __restrict__ src,
                      const int* __restrict__ band,
                      int* __restrict__ deg, int* __restrict__ pk){
  int e = blockIdx.x*blockDim.x + threadIdx.x;
  if (e < E_){
    atomicAdd(&deg[dst[e]], 1);
    pk[e] = src[e] | (band[e] << 16);
  }
}

__global__ __launch_bounds__(1024)
void k_scan1(const int* __restrict__ deg, int* __restrict__ rowptr,
             int* __restrict__ bsum){
  __shared__ int sm[1024];
  int b = blockIdx.x, tid = threadIdx.x;
  int i = b*1024 + tid;
  int v = (i < N_) ? deg[i] : 0;
  sm[tid] = v; __syncthreads();
  for (int off=1; off<1024; off<<=1){
    int t = (tid>=off) ? sm[tid-off] : 0;
    __syncthreads();
    sm[tid] += t;
    __syncthreads();
  }
  if (i < N_) rowptr[i+1] = sm[tid];
  if (tid == 1023) bsum[b] = sm[1023];
}

__global__ void k_scan2(int* __restrict__ bsum, int nb){
  int tid = threadIdx.x;
  int v = (tid < nb) ? bsum[tid] : 0;
  for (int off=1; off<64; off<<=1){
    int t = __shfl_up(v, off, 64);
    if (tid >= off) v += t;
  }
  if (tid < nb) bsum[tid] = v;
}

__global__ void k_scan3(int* __restrict__ rowptr, const int* __restrict__ bsum){
  int i = blockIdx.x*blockDim.x + threadIdx.x;
  if (i == 0) rowptr[0] = 0;
  if (i < N_){
    int b = i >> 10;
    if (b > 0) rowptr[i+1] += bsum[b-1];
  }
}

__global__ void k_scatter(const int* __restrict__ dst, const int* __restrict__ rowptr,
                          int* __restrict__ fill, int* __restrict__ eord){
  int e = blockIdx.x*blockDim.x + threadIdx.x;
  if (e < E_){
    int d = dst[e];
    int pos = rowptr[d] + atomicAdd(&fill[d], 1);
    eord[pos] = e;
  }
}

__global__ void k_sortseg(const int* __restrict__ rowptr, int* __restrict__ eord){
  int i = blockIdx.x*blockDim.x + threadIdx.x;
  if (i >= N_) return;
  int b = rowptr[i], t = rowptr[i+1];
  for (int p = b+1; p < t; p++){
    int v = eord[p];
    int q = p-1;
    while (q >= b && eord[q] > v){ eord[q+1] = eord[q]; q--; }
    eord[q+1] = v;
  }
}

// CSR-ordered edge meta: em[p] = (src|band<<16, eattr bits)
__global__ void k_emeta(const int* __restrict__ eord, const int* __restrict__ pk,
                        const float* __restrict__ eattr, int2* __restrict__ em){
  int p = blockIdx.x*blockDim.x + threadIdx.x;
  if (p < E_){
    int e = eord[p];
    em[p] = make_int2(pk[e], __float_as_int(eattr[e]));
  }
}

// ---------------- direct-global bf16 MFMA GEMM: C = A(Mx128) @ W(128x128) ----------------
// BM=128, 512 threads = 8 waves, wave tile 64x32 (acc[4][2]). W packed-fragment.
// EPI: 3 = bias -> f32 | 4 = QKV: by0 -> Q bf16 ld128; by1/2 -> K/V fp8 into [N][256B]
template<int EPI>
__global__ __launch_bounds__(512, 2)
void gemm128_direct(const short* __restrict__ A, const short* __restrict__ Wt,
                    const float* __restrict__ bias,
                    float* Cf, short* Yb, unsigned char* KV8, int M, long wstride){
  const int tid = threadIdx.x;
  const int by  = blockIdx.y;
  Wt += (size_t)by * wstride;
  const short8* W8 = (const short8*)Wt;
  const int m0 = blockIdx.x * 128;
  const int lane = tid & 63, w = tid >> 6;
  const int wr = w >> 2, wc = w & 3;
  const int lrow = lane & 15, lgrp = lane >> 4;
  f32x4 acc[4][2];
  #pragma unroll
  for (int r=0;r<4;r++){ acc[r][0] = {0.f,0.f,0.f,0.f}; acc[r][1] = {0.f,0.f,0.f,0.f}; }
  int rowA[4];
  #pragma unroll
  for (int r=0;r<4;r++){
    int rr = m0 + wr*64 + r*16 + lrow;
    rowA[r] = (rr < M) ? rr : (M-1);
  }
  #pragma unroll
  for (int kk = 0; kk < 4; kk++){
    const int koff = kk*32 + lgrp*8;
    short8 af[4], bfr[2];
    #pragma unroll
    for (int r = 0; r < 4; r++)
      af[r] = *(const short8*)(A + (size_t)rowA[r]*128 + koff);
    #pragma unroll
    for (int c = 0; c < 2; c++)
      bfr[c] = W8[(size_t)(wc*2 + c)*256 + kk*64 + lane];
    #pragma unroll
    for (int r = 0; r < 4; r++)
      #pragma unroll
      for (int c = 0; c < 2; c++)
        acc[r][c] = __builtin_amdgcn_mfma_f32_16x16x32_bf16(af[r], bfr[c], acc[r][c], 0, 0, 0);
  }
  #pragma unroll
  for (int r = 0; r < 4; r++){
    #pragma unroll
    for (int c = 0; c < 2; c++){
      int col = wc*32 + c*16 + lrow;
      float bv = (EPI == 3) ? bias[col] : 0.f;
      #pragma unroll
      for (int v = 0; v < 4; v++){
        int row = m0 + wr*64 + r*16 + lgrp*4 + v;
        if (row < M){
          float o = acc[r][c][v] + bv;
          if (EPI == 3) Cf[(size_t)row*128 + col] = o;
          else if (by == 0) Yb[(size_t)row*128 + col] = f2bf(o);
          else KV8[(size_t)row*256 + (by-1)*128 + col] = f2fp8(o);
        }
      }
    }
  }
}

// ---------------- FUSED layer tail (BM=32, 4 waves, (256,4) -> 64-VGPR cap) ----------
// hb = LN2( FFN(LN1(aggb@Wo + b + hb)) + LN1out )
// Phase A: Wo GEMM + bf16 residual + register-LN1 -> y bf16 -> ytile (8KB).
// Phase B: 4-chunk FFN; A-frags from ytile; hidden single-buffer (8KB).
// Phase C: register-LN2 (residual from ytile) -> hb. LDS ~17.4KB; actual ~8 blocks/CU.
__global__ __launch_bounds__(256, 4)
void wo_ffn_fused(const short* __restrict__ aggb, const short* __restrict__ wot,
                  const float* __restrict__ wo_b, short* __restrict__ hb,
                  const short* __restrict__ w1t, const float* __restrict__ b1,
                  const short* __restrict__ w2t, const float* __restrict__ b2,
                  const float* __restrict__ g1, const float* __restrict__ bl1,
                  const float* __restrict__ g2, const float* __restrict__ bl2,
                  int M){
  __shared__ char ytile[8192];
  __shared__ char hidb[8192];
  __shared__ float rsum[4][32];
  __shared__ float rsq[4][32];
  const int tid = threadIdx.x;
  const int m0 = blockIdx.x * 32;
  const int lane = tid & 63, w = tid >> 6;     // w in 0..3 (col-wave)
  const int lrow = lane & 15, lgrp = lane >> 4;
  int rowA[2];
  #pragma unroll
  for (int r=0;r<2;r++){
    int rr = m0 + r*16 + lrow;
    rowA[r] = (rr < M) ? rr : (M-1);
  }

  // ---------- Phase A: Wo GEMM + residual + LN1 -> ytile ----------
  {
    const short8* W8 = (const short8*)wot;
    f32x4 acc[2][2];
    #pragma unroll
    for (int r=0;r<2;r++){ acc[r][0] = {0.f,0.f,0.f,0.f}; acc[r][1] = {0.f,0.f,0.f,0.f}; }
    #pragma unroll
    for (int kk = 0; kk < 4; kk++){
      const int koff = kk*32 + lgrp*8;
      short8 af[2], bfr[2];
      #pragma unroll
      for (int r = 0; r < 2; r++)
        af[r] = *(const short8*)(aggb + (size_t)rowA[r]*128 + koff);
      #pragma unroll
      for (int c = 0; c < 2; c++)
        bfr[c] = W8[(size_t)(w*2 + c)*256 + kk*64 + lane];
      #pragma unroll
      for (int r = 0; r < 2; r++)
        #pragma unroll
        for (int c = 0; c < 2; c++)
          acc[r][c] = __builtin_amdgcn_mfma_f32_16x16x32_bf16(af[r], bfr[c], acc[r][c], 0, 0, 0);
    }
    float o[2][2][4];
    float ps[2][4], pq[2][4];
    #pragma unroll
    for (int r=0;r<2;r++)
      #pragma unroll
      for (int v=0;v<4;v++){ ps[r][v]=0.f; pq[r][v]=0.f; }
    #pragma unroll
    for (int r = 0; r < 2; r++){
      #pragma unroll
      for (int c = 0; c < 2; c++){
        int col = w*32 + c*16 + lrow;
        float bv = wo_b[col];
        #pragma unroll
        for (int v = 0; v < 4; v++){
          int grow = m0 + r*16 + lgrp*4 + v;
          int gr = (grow < M) ? grow : (M-1);
          float oo = acc[r][c][v] + bv + bf2f(hb[(size_t)gr*128 + col]);
          o[r][c][v] = oo;
          ps[r][v] += oo;
          pq[r][v] += oo*oo;
        }
      }
    }
    #pragma unroll
    for (int r = 0; r < 2; r++)
      #pragma unroll
      for (int v = 0; v < 4; v++){
        #pragma unroll
        for (int off = 1; off < 16; off <<= 1){
          ps[r][v] += __shfl_xor(ps[r][v], off, 16);
          pq[r][v] += __shfl_xor(pq[r][v], off, 16);
        }
      }
    if (lrow == 0){
      #pragma unroll
      for (int r = 0; r < 2; r++)
        #pragma unroll
        for (int v = 0; v < 4; v++){
          int row = r*16 + lgrp*4 + v;
          rsum[w][row] = ps[r][v];
          rsq[w][row]  = pq[r][v];
        }
    }
    __syncthreads();                         // stats ready
    #pragma unroll
    for (int r = 0; r < 2; r++){
      float gv[2], bv2[2];
      #pragma unroll
      for (int c = 0; c < 2; c++){
        int col = w*32 + c*16 + lrow;
        gv[c] = g1[col]; bv2[c] = bl1[col];
      }
      #pragma unroll
      for (int v = 0; v < 4; v++){
        int row = r*16 + lgrp*4 + v;
        float s = (rsum[0][row]+rsum[1][row]) + (rsum[2][row]+rsum[3][row]);
        float q = (rsq[0][row]+rsq[1][row]) + (rsq[2][row]+rsq[3][row]);
        float mean = s * (1.f/128.f);
        float var  = q * (1.f/128.f) - mean*mean;
        float rstd = rsqrtf(var + 1e-5f);
        #pragma unroll
        for (int c = 0; c < 2; c++){
          int col = w*32 + c*16 + lrow;
          float y = (o[r][c][v] - mean)*rstd*gv[c] + bv2[c];
          int off = row*256 + col*2;
          *(short*)(ytile + (off ^ ((row & 7) << 4))) = f2bf(y);
        }
      }
    }
  }
  __syncthreads();                           // ytile ready

  // ---------- Phase B: FFN over 4 chunks of 128 hidden cols ----------
  const short8* W18 = (const short8*)w1t;
  const short8* W28 = (const short8*)w2t;
  f32x4 acc2[2][2];
  #pragma unroll
  for (int r=0;r<2;r++){ acc2[r][0] = {0.f,0.f,0.f,0.f}; acc2[r][1] = {0.f,0.f,0.f,0.f}; }
  #pragma unroll
  for (int chunk = 0; chunk < 4; chunk++){
    f32x4 acc1[2][2];
    #pragma unroll
    for (int r=0;r<2;r++){ acc1[r][0] = {0.f,0.f,0.f,0.f}; acc1[r][1] = {0.f,0.f,0.f,0.f}; }
    #pragma unroll
    for (int kk = 0; kk < 4; kk++){
      const int kbyt = kk*64 + lgrp*16;
      short8 af[2], bfr[2];
      #pragma unroll
      for (int r = 0; r < 2; r++){
        int row = r*16 + lrow;                 // local row 0..31
        af[r] = *(const short8*)(ytile + ((row*256 + kbyt) ^ ((row & 7) << 4)));
      }
      #pragma unroll
      for (int c = 0; c < 2; c++){
        int nb = chunk*8 + w*2 + c;            // n1/16
        bfr[c] = W18[(size_t)nb*256 + kk*64 + lane];
      }
      #pragma unroll
      for (int r = 0; r < 2; r++)
        #pragma unroll
        for (int c = 0; c < 2; c++)
          acc1[r][c] = __builtin_amdgcn_mfma_f32_16x16x32_bf16(af[r], bfr[c], acc1[r][c], 0, 0, 0);
    }
    __syncthreads();                     // prev chunk's FFN2 hidden reads done
    #pragma unroll
    for (int r = 0; r < 2; r++){
      #pragma unroll
      for (int c = 0; c < 2; c++){
        int lc = w*32 + c*16 + lrow;           // chunk-local col
        float bv = b1[chunk*128 + lc];
        #pragma unroll
        for (int v = 0; v < 4; v++){
          int row = r*16 + lgrp*4 + v;
          float g = gelu_f(acc1[r][c][v] + bv);
          int off = row*256 + lc*2;
          *(short*)(hidb + (off ^ ((row & 7) << 4))) = f2bf(g);
        }
      }
    }
    __syncthreads();                     // hidden ready
    #pragma unroll
    for (int kk2 = 0; kk2 < 4; kk2++){
      short8 ah[2], bh[2];
      #pragma unroll
      for (int r = 0; r < 2; r++){
        int row = r*16 + lrow;
        ah[r] = *(const short8*)(hidb + ((row*256 + kk2*64 + lgrp*16) ^ ((row & 7) << 4)));
      }
      #pragma unroll
      for (int c = 0; c < 2; c++){
        int nb = w*2 + c;                      // n2/16
        bh[c] = W28[(size_t)nb*1024 + chunk*256 + kk2*64 + lane];
      }
      #pragma unroll
      for (int r = 0; r < 2; r++)
        #pragma unroll
        for (int c = 0; c < 2; c++)
          acc2[r][c] = __builtin_amdgcn_mfma_f32_16x16x32_bf16(ah[r], bh[c], acc2[r][c], 0, 0, 0);
    }
  }

  // ---------- Phase C: LN2 (residual = ytile) -> hb ----------
  {
    float o2[2][2][4];
    float ps[2][4], pq[2][4];
    #pragma unroll
    for (int r=0;r<2;r++)
      #pragma unroll
      for (int v=0;v<4;v++){ ps[r][v]=0.f; pq[r][v]=0.f; }
    #pragma unroll
    for (int r = 0; r < 2; r++){
      #pragma unroll
      for (int c = 0; c < 2; c++){
        int col = w*32 + c*16 + lrow;
        float bv = b2[col];
        #pragma unroll
        for (int v = 0; v < 4; v++){
          int row = r*16 + lgrp*4 + v;
          int off = row*256 + col*2;
          float res = bf2f(*(const short*)(ytile + (off ^ ((row & 7) << 4))));
          float oo = acc2[r][c][v] + bv + res;
          o2[r][c][v] = oo;
          ps[r][v] += oo;
          pq[r][v] += oo*oo;
        }
      }
    }
    #pragma unroll
    for (int r = 0; r < 2; r++)
      #pragma unroll
      for (int v = 0; v < 4; v++){
        #pragma unroll
        for (int off = 1; off < 16; off <<= 1){
          ps[r][v] += __shfl_xor(ps[r][v], off, 16);
          pq[r][v] += __shfl_xor(pq[r][v], off, 16);
        }
      }
    __syncthreads();                         // guard rsum reuse
    if (lrow == 0){
      #pragma unroll
      for (int r = 0; r < 2; r++)
        #pragma unroll
        for (int v = 0; v < 4; v++){
          int row = r*16 + lgrp*4 + v;
          rsum[w][row] = ps[r][v];
          rsq[w][row]  = pq[r][v];
        }
    }
    __syncthreads();
    #pragma unroll
    for (int r = 0; r < 2; r++){
      float gv[2], bv2[2];
      #pragma unroll
      for (int c = 0; c < 2; c++){
        int col = w*32 + c*16 + lrow;
        gv[c] = g2[col]; bv2[c] = bl2[col];
      }
      #pragma unroll
      for (int v = 0; v < 4; v++){
        int row = r*16 + lgrp*4 + v;
        int grow = m0 + row;
        float s = (rsum[0][row]+rsum[1][row]) + (rsum[2][row]+rsum[3][row]);
        float q = (rsq[0][row]+rsq[1][row]) + (rsq[2][row]+rsq[3][row]);
        float mean = s * (1.f/128.f);
        float var  = q * (1.f/128.f) - mean*mean;
        float rstd = rsqrtf(var + 1e-5f);
        if (grow < M){
          #pragma unroll
          for (int c = 0; c < 2; c++){
            int col = w*32 + c*16 + lrow;
            float y = (o2[r][c][v] - mean)*rstd*gv[c] + bv2[c];
            hb[(size_t)grow*128 + col] = f2bf(y);
          }
        }
      }
    }
  }
}

// ---------------- fused per-node attention: 4 chains, (256,8), fp8 K/V, CSR meta ------
__global__ __launch_bounds__(256, 8)
void attn_fused(const short* __restrict__ Qb, const unsigned char* __restrict__ KV8,
                const int2* __restrict__ em,
                const int* __restrict__ rowptr,
                const float* __restrict__ bb_l, short* __restrict__ aggb){
  const int lane = threadIdx.x & 63;
  const int i = (blockIdx.x << 2) + (threadIdx.x >> 6);
  if (i >= N_) return;
  const int hh = lane >> 3;
  const unsigned qw = ((const unsigned*)Qb)[(size_t)i*64 + lane];
  const float q0 = bflo(qw), q1 = bfhi(qw);
  const int p0 = __builtin_amdgcn_readfirstlane(rowptr[i]);
  const int p1 = __builtin_amdgcn_readfirstlane(rowptr[i+1]);
  constexpr float L2E = 1.442695040888963f;
  float2 outv = {0.f, 0.f};
  if (p0 < p1){
    float s[4]; float2 acc[4];
    #pragma unroll
    for (int c=0;c<4;c++){ s[c]=0.f; acc[c].x=0.f; acc[c].y=0.f; }
    int sj[4], sjN[4];
    float bb[4], ea[4], bbN[4], eaN[4];
    int kw[4], vw[4], kwN[4], vwN[4];

    auto ldmeta = [&](int gb, int* SJ, float* BB, float* EA){
      #pragma unroll
      for (int c = 0; c < 4; c++){
        int idx = gb + c; idx = (idx < p1) ? idx : (p1 - 1);
        int2 m = em[idx];
        unsigned u = (unsigned)__builtin_amdgcn_readfirstlane(m.x);
        SJ[c] = (int)(u & 0xFFFFu);
        BB[c] = bb_l[(u >> 16)*H_ + hh];
        EA[c] = __uint_as_float((unsigned)__builtin_amdgcn_readfirstlane(m.y));
      }
    };

    ldmeta(p0, sj, bb, ea);
    #pragma unroll
    for (int c = 0; c < 4; c++){
      kw[c] = *(const unsigned short*)(KV8 + (size_t)sj[c]*256 + lane*2);
      vw[c] = *(const unsigned short*)(KV8 + (size_t)sj[c]*256 + 128 + lane*2);
    }
    ldmeta(p0 + 4, sjN, bbN, eaN);

    for (int base = p0; base < p1; base += 4){
      #pragma unroll
      for (int c = 0; c < 4; c++){
        kwN[c] = *(const unsigned short*)(KV8 + (size_t)sjN[c]*256 + lane*2);
        vwN[c] = *(const unsigned short*)(KV8 + (size_t)sjN[c]*256 + 128 + lane*2);
      }
      int sj2[4]; float bb2[4], ea2[4];
      ldmeta(base + 8, sj2, bb2, ea2);
      #pragma unroll
      for (int c = 0; c < 4; c++){
        f32x2 kf = __builtin_amdgcn_cvt_pk_f32_fp8(kw[c], false);
        float dot = q0*kf[0] + q1*kf[1];
        dot += __shfl_xor(dot, 1, 8);
        dot += __shfl_xor(dot, 2, 8);
        dot += __shfl_xor(dot, 4, 8);
        float logit = (dot*0.25f + bb[c]) * ea[c];
        logit = fminf(logit, 60.f);
        if (base + c >= p1) logit = -1.0e30f;   // tail slot -> weight 0
        float wgt = exp2f(logit * L2E);
        f32x2 vf = __builtin_amdgcn_cvt_pk_f32_fp8(vw[c], false);
        s[c]     += wgt;
        acc[c].x += wgt*vf[0];
        acc[c].y += wgt*vf[1];
      }
      #pragma unroll
      for (int c = 0; c < 4; c++){
        kw[c]=kwN[c]; vw[c]=vwN[c];
        sj[c]=sjN[c]; bb[c]=bbN[c]; ea[c]=eaN[c];
        sjN[c]=sj2[c]; bbN[c]=bb2[c]; eaN[c]=ea2[c];
      }
    }
    float S = (s[0]+s[1]) + (s[2]+s[3]);
    float Ax = (acc[0].x+acc[1].x) + (acc[2].x+acc[3].x);
    float Ay = (acc[0].y+acc[1].y) + (acc[2].y+acc[3].y);
    float inv = 1.0f / (S + 1e-16f);
    outv.x = Ax * inv;
    outv.y = Ay * inv;
  }
  unsigned lo = (unsigned)(unsigned short)f2bf(outv.x);
  unsigned hi = (unsigned)(unsigned short)f2bf(outv.y);
  ((unsigned*)aggb)[(size_t)i*64 + lane] = lo | (hi << 16);
}

extern "C" void kernel_launch(void* const* d_in, const int* in_sizes, int n_in,
                              void* d_out, int out_size, void* d_ws, size_t ws_size,
                              hipStream_t stream) {
  const float* x         = (const float*)d_in[0];
  const int*   edge_index= (const int*)  d_in[1];
  const float* edge_attr = (const float*)d_in[2];
  const int*   band_ids  = (const int*)  d_in[3];
  const int*   stage_ids = (const int*)  d_in[4];
  const float* stage_emb = (const float*)d_in[5];
  const float* in_w      = (const float*)d_in[6];
  const float* in_b      = (const float*)d_in[7];
  const float* Wq        = (const float*)d_in[8];
  const float* Wk        = (const float*)d_in[9];
  const float* Wv        = (const float*)d_in[10];
  const float* Wo        = (const float*)d_in[11];
  const float* Wo_b      = (const float*)d_in[12];
  const float* band_bias = (const float*)d_in[13];
  const float* ln1_g     = (const float*)d_in[14];
  const float* ln1_b     = (const float*)d_in[15];
  const float* ffn_w1    = (const float*)d_in[16];
  const float* ffn_b1    = (const float*)d_in[17];
  const float* ffn_w2    = (const float*)d_in[18];
  const float* ffn_b2    = (const float*)d_in[19];
  const float* ln2_g     = (const float*)d_in[20];
  const float* ln2_b     = (const float*)d_in[21];
  const float* out_w     = (const float*)d_in[22];
  const float* out_b     = (const float*)d_in[23];
  float* out = (float*)d_out;

  const size_t ND = (size_t)N_*D_;           // 6.4M
  float* ws  = (float*)d_ws;
  short* hb   = (short*)ws;                  // bf16 N x 128 (ONLY hidden state)
  short* aggb = (short*)(ws + ND);           // bf16 N x 128
  short* qb   = (short*)(ws + 2*ND);         // bf16 Q N x 128
  unsigned char* kv8 = (unsigned char*)(ws + 2*ND + ND/2);  // fp8 KV [N][256B]
  short* wbuf = (short*)(ws + 3*ND + ND/2);  // packed bf16 weights: 802816 shorts
  short* wqkvt = wbuf;
  short* wot   = wbuf + 196608;
  short* w1t   = wbuf + 262144;
  short* w2t   = wbuf + 524288;
  short* owt   = wbuf + 786432;
  int*  ibase = (int*)(ws + 3*ND + ND/2 + 401408);
  int*  deg   = ibase;                       // N
  int*  fill  = ibase + N_;                  // N
  int*  rowptr= ibase + 2*N_;                // N+1
  int*  eord  = ibase + 3*N_ + 1;            // E
  int*  bsum  = ibase + 3*N_ + 1 + E_;       // 64
  int*  pk    = ibase + 3*N_ + 1 + E_ + 64;  // E
  int2* em    = (int2*)(ibase + 3*N_ + 1 + 2*E_ + 64);  // E int2

  const int* srcA = edge_index;
  const int* dstA = edge_index + E_;

  hipMemsetAsync(deg, 0, 2ull*N_*sizeof(int), stream);

  conv_weights<<<3136, 256, 0, stream>>>(Wq, Wk, Wv, Wo, ffn_w1, ffn_w2, out_w,
                                         wqkvt, wot, w1t, w2t, owt);
  input_proj<<<N_/2, 256, 0, stream>>>(x, in_w, in_b, stage_emb, stage_ids, hb);

  k_deg   <<<(E_+255)/256, 256, 0, stream>>>(dstA, srcA, band_ids, deg, pk);
  k_scan1 <<<49, 1024, 0, stream>>>(deg, rowptr, bsum);
  k_scan2 <<<1, 64, 0, stream>>>(bsum, 49);
  k_scan3 <<<(N_+255)/256, 256, 0, stream>>>(rowptr, bsum);
  k_scatter<<<(E_+255)/256, 256, 0, stream>>>(dstA, rowptr, fill, eord);
  k_sortseg<<<(N_+255)/256, 256, 0, stream>>>(rowptr, eord);
  k_emeta <<<(E_+255)/256, 256, 0, stream>>>(eord, pk, edge_attr, em);

  const int GB  = (N_ + 127) / 128;          // 391
  const int GB3 = (N_ + 31) / 32;            // 1563
  const int AB  = (N_ + 3) / 4;              // 12500

  for (int l = 0; l < L_; l++){
    // Q (bf16 ld128) + K/V (fp8 interleaved [N][256B]) from hb
    gemm128_direct<4><<<dim3(GB,3), 512, 0, stream>>>(
        hb, wqkvt + (size_t)l*3*16384, nullptr, nullptr, qb, kv8, N_, 16384L);

    attn_fused<<<AB, 256, 0, stream>>>(qb, kv8, em, rowptr,
                                       band_bias + l*NB_*H_, aggb);

    // hb = LN2( FFN(LN1(aggb@Wo + b + hb)) + LN1out )   — one fused kernel, BM=32
    wo_ffn_fused<<<GB3, 256, 0, stream>>>(
        aggb, wot + (size_t)l*16384, Wo_b + l*D_, hb,
        w1t + (size_t)l*65536, ffn_b1 + l*DFF_,
        w2t + (size_t)l*65536, ffn_b2 + l*D_,
        ln1_g + l*D_, ln1_b + l*D_, ln2_g + l*D_, ln2_b + l*D_, N_);
  }

  gemm128_direct<3><<<GB, 512, 0, stream>>>(
      hb, owt, out_b, out, nullptr, nullptr, N_, 0L);
}

// Round 23
// 657.257 us; speedup vs baseline: 1.1863x; 1.0648x over previous
//
#include <hip/hip_runtime.h>
#include <math.h>

constexpr int N_   = 50000;
constexpr int E_   = 800000;
constexpr int FIN_ = 32;
constexpr int D_   = 128;
constexpr int H_   = 8;
constexpr int NB_  = 5;
constexpr int L_   = 4;
constexpr int DFF_ = 512;

typedef __attribute__((ext_vector_type(8))) short short8;
typedef __attribute__((ext_vector_type(4))) short short4v;
typedef __attribute__((ext_vector_type(4))) float f32x4;
typedef __attribute__((ext_vector_type(2))) float f32x2;

__device__ __forceinline__ short f2bf(float f){
  unsigned u = __float_as_uint(f);
  unsigned r = (u + 0x7FFFu + ((u >> 16) & 1u)) >> 16;
  return (short)r;
}
__device__ __forceinline__ float bf2f(short v){
  return __uint_as_float(((unsigned)(unsigned short)v) << 16);
}
__device__ __forceinline__ float bflo(unsigned u){ return __uint_as_float(u << 16); }
__device__ __forceinline__ float bfhi(unsigned u){ return __uint_as_float(u & 0xffff0000u); }

// fp8 e4m3 encode via gfx950 HW converts (self-consistent with decode)
__device__ __forceinline__ unsigned char f2fp8(float x){
  int p = __builtin_amdgcn_cvt_pk_fp8_f32(x, x, 0, false);
  return (unsigned char)(p & 0xFF);
}

// inline exact-gelu via A&S 7.1.26 erf (|err|<1.5e-7)
__device__ __forceinline__ float gelu_f(float x){
  float xs = x * 0.70710678118654752f;
  float ax = fabsf(xs);
  float t  = __builtin_amdgcn_rcpf(1.0f + 0.3275911f*ax);
  float y  = t*(0.254829592f + t*(-0.284496736f + t*(1.421413741f +
             t*(-1.453152027f + t*1.061405429f))));
  float e  = exp2f(-ax*ax*1.4426950408889634f);
  float er = 1.0f - y*e;
  er = __uint_as_float((__float_as_uint(er) & 0x7fffffffu) |
                       (__float_as_uint(xs) & 0x80000000u));
  return 0.5f*x*(1.0f + er);
}

// packed-fragment weight index: wave B-frag load = ONE coalesced 1KB read
__device__ __forceinline__ size_t pfidx(int n, int k, int K){
  return ((size_t)(n >> 4)*(2*K) + (size_t)(k >> 3)*16 + (n & 15))*8 + (k & 7);
}

// ---------------- weight convert + transpose to packed bf16 (once per call) ----------------
__global__ __launch_bounds__(256)
void conv_weights(const float* __restrict__ Wq, const float* __restrict__ Wk,
                  const float* __restrict__ Wv, const float* __restrict__ Wo,
                  const float* __restrict__ w1, const float* __restrict__ w2,
                  const float* __restrict__ ow,
                  short* __restrict__ wqkvt, short* __restrict__ wot,
                  short* __restrict__ w1t, short* __restrict__ w2t,
                  short* __restrict__ owt){
  int idx = blockIdx.x * blockDim.x + threadIdx.x;
  if (idx < 3*L_*16384){
    int m = idx / (L_*16384);
    int r = idx % (L_*16384);
    int l = r / 16384, e = r % 16384;
    int k = e >> 7, n = e & 127;
    const float* src = (m == 0) ? Wq : ((m == 1) ? Wk : Wv);
    wqkvt[(size_t)(l*3 + m)*16384 + pfidx(n, k, 128)] = f2bf(src[(size_t)l*16384 + e]);
    return;
  }
  idx -= 3*L_*16384;
  if (idx < L_*16384){
    int l = idx / 16384, e = idx % 16384, k = e >> 7, n = e & 127;
    wot[(size_t)l*16384 + pfidx(n, k, 128)] = f2bf(Wo[idx]);
    return;
  }
  idx -= L_*16384;
  if (idx < L_*D_*DFF_){            // w1: K=128 N=512
    int l = idx / 65536, e = idx % 65536;
    int k = e >> 9, n = e & 511;
    w1t[(size_t)l*65536 + pfidx(n, k, 128)] = f2bf(w1[idx]);
    return;
  }
  idx -= L_*D_*DFF_;
  if (idx < L_*DFF_*D_){            // w2: K=512 N=128
    int l = idx / 65536, e = idx % 65536;
    int k = e >> 7, n = e & 127;
    w2t[(size_t)l*65536 + pfidx(n, k, 512)] = f2bf(w2[idx]);
    return;
  }
  idx -= L_*DFF_*D_;
  if (idx < 16384){
    int k = idx >> 7, n = idx & 127;
    owt[pfidx(n, k, 128)] = f2bf(ow[idx]);
  }
}

// ---------------- input projection (2 nodes / block) ----------------
__global__ __launch_bounds__(256)
void input_proj(const float* __restrict__ x, const float* __restrict__ in_w,
                const float* __restrict__ in_b, const float* __restrict__ se,
                const int* __restrict__ sid, short* __restrict__ hb){
  int sub = threadIdx.x >> 7, d = threadIdx.x & 127;
  int i = blockIdx.x*2 + sub;
  __shared__ float xs[2][FIN_];
  if (d < FIN_) xs[sub][d] = x[(size_t)i*FIN_ + d];
  __syncthreads();
  float acc = in_b[d] + se[(size_t)sid[i]*D_ + d];
  #pragma unroll 8
  for (int k=0;k<FIN_;k++) acc += xs[sub][k]*in_w[k*D_+d];
  hb[(size_t)i*D_+d] = f2bf(acc);
}

// ---------------- CSR build ----------------
__global__ void k_deg(const int* __restrict__ dst, const int* __restrict__ src,
                      const int* __restrict__ band,
                      int* __restrict__ deg, int* __restrict__ pk){
  int e = blockIdx.x*blockDim.x + threadIdx.x;
  if (e < E_){
    atomicAdd(&deg[dst[e]], 1);
    pk[e] = src[e] | (band[e] << 16);
  }
}

__global__ __launch_bounds__(1024)
void k_scan1(const int* __restrict__ deg, int* __restrict__ rowptr,
             int* __restrict__ bsum){
  __shared__ int sm[1024];
  int b = blockIdx.x, tid = threadIdx.x;
  int i = b*1024 + tid;
  int v = (i < N_) ? deg[i] : 0;
  sm[tid] = v; __syncthreads();
  for (int off=1; off<1024; off<<=1){
    int t = (tid>=off) ? sm[tid-off] : 0;
    __syncthreads();
    sm[tid] += t;
    __syncthreads();
  }
  if (i < N_) rowptr[i+1] = sm[tid];
  if (tid == 1023) bsum[b] = sm[1023];
}

__global__ void k_scan2(int* __restrict__ bsum, int nb){
  int tid = threadIdx.x;
  int v = (tid < nb) ? bsum[tid] : 0;
  for (int off=1; off<64; off<<=1){
    int t = __shfl_up(v, off, 64);
    if (tid >= off) v += t;
  }
  if (tid < nb) bsum[tid] = v;
}

__global__ void k_scan3(int* __restrict__ rowptr, const int* __restrict__ bsum){
  int i = blockIdx.x*blockDim.x + threadIdx.x;
  if (i == 0) rowptr[0] = 0;
  if (i < N_){
    int b = i >> 10;
    if (b > 0) rowptr[i+1] += bsum[b-1];
  }
}

__global__ void k_scatter(const int* __restrict__ dst, const int* __restrict__ rowptr,
                          int* __restrict__ fill, int* __restrict__ eord){
  int e = blockIdx.x*blockDim.x + threadIdx.x;
  if (e < E_){
    int d = dst[e];
    int pos = rowptr[d] + atomicAdd(&fill[d], 1);
    eord[pos] = e;
  }
}

__global__ void k_sortseg(const int* __restrict__ rowptr, int* __restrict__ eord){
  int i = blockIdx.x*blockDim.x + threadIdx.x;
  if (i >= N_) return;
  int b = rowptr[i], t = rowptr[i+1];
  for (int p = b+1; p < t; p++){
    int v = eord[p];
    int q = p-1;
    while (q >= b && eord[q] > v){ eord[q+1] = eord[q]; q--; }
    eord[q+1] = v;
  }
}

// CSR-ordered edge meta: em[p] = (src|band<<16, eattr bits)
__global__ void k_emeta(const int* __restrict__ eord, const int* __restrict__ pk,
                        const float* __restrict__ eattr, int2* __restrict__ em){
  int p = blockIdx.x*blockDim.x + threadIdx.x;
  if (p < E_){
    int e = eord[p];
    em[p] = make_int2(pk[e], __float_as_int(eattr[e]));
  }
}

// ---------------- direct-global bf16 MFMA GEMM: C = A(Mx128) @ W(128x128) ----------------
// BM=128, 512 threads = 8 waves, wave tile 64x32 (acc[4][2]). W packed-fragment.
// EPI: 3 = bias -> f32 | 4 = QKV: by0 -> Q bf16 ld128; by1/2 -> K/V fp8 into [N][256B]
template<int EPI>
__global__ __launch_bounds__(512, 2)
void gemm128_direct(const short* __restrict__ A, const short* __restrict__ Wt,
                    const float* __restrict__ bias,
                    float* Cf, short* Yb, unsigned char* KV8, int M, long wstride){
  const int tid = threadIdx.x;
  const int by  = blockIdx.y;
  Wt += (size_t)by * wstride;
  const short8* W8 = (const short8*)Wt;
  const int m0 = blockIdx.x * 128;
  const int lane = tid & 63, w = tid >> 6;
  const int wr = w >> 2, wc = w & 3;
  const int lrow = lane & 15, lgrp = lane >> 4;
  f32x4 acc[4][2];
  #pragma unroll
  for (int r=0;r<4;r++){ acc[r][0] = {0.f,0.f,0.f,0.f}; acc[r][1] = {0.f,0.f,0.f,0.f}; }
  int rowA[4];
  #pragma unroll
  for (int r=0;r<4;r++){
    int rr = m0 + wr*64 + r*16 + lrow;
    rowA[r] = (rr < M) ? rr : (M-1);
  }
  #pragma unroll
  for (int kk = 0; kk < 4; kk++){
    const int koff = kk*32 + lgrp*8;
    short8 af[4], bfr[2];
    #pragma unroll
    for (int r = 0; r < 4; r++)
      af[r] = *(const short8*)(A + (size_t)rowA[r]*128 + koff);
    #pragma unroll
    for (int c = 0; c < 2; c++)
      bfr[c] = W8[(size_t)(wc*2 + c)*256 + kk*64 + lane];
    #pragma unroll
    for (int r = 0; r < 4; r++)
      #pragma unroll
      for (int c = 0; c < 2; c++)
        acc[r][c] = __builtin_amdgcn_mfma_f32_16x16x32_bf16(af[r], bfr[c], acc[r][c], 0, 0, 0);
  }
  #pragma unroll
  for (int r = 0; r < 4; r++){
    #pragma unroll
    for (int c = 0; c < 2; c++){
      int col = wc*32 + c*16 + lrow;
      float bv = (EPI == 3) ? bias[col] : 0.f;
      #pragma unroll
      for (int v = 0; v < 4; v++){
        int row = m0 + wr*64 + r*16 + lgrp*4 + v;
        if (row < M){
          float o = acc[r][c][v] + bv;
          if (EPI == 3) Cf[(size_t)row*128 + col] = o;
          else if (by == 0) Yb[(size_t)row*128 + col] = f2bf(o);
          else KV8[(size_t)row*256 + (by-1)*128 + col] = f2fp8(o);
        }
      }
    }
  }
}

// ---------------- FUSED layer tail (BM=32, 4 waves, (256,4)): ----------------
// hb = LN2( FFN(LN1(aggb@Wo + b + hb)) + LN1out );  optional Phase D: next-layer QKV
// Phase A: Wo GEMM + bf16 residual + register-LN1 -> y bf16 -> ytile (8KB).
// Phase B: 4-chunk FFN; A-frags from ytile; hidden single-buffer (8KB).
// Phase C: register-LN2 (residual from ytile) -> hb AND ytile (same addrs).
// Phase D (if qkvw): Q/K/V(l+1) = ytile @ Wq/Wk/Wv -> qb bf16 / kv8 fp8.
__global__ __launch_bounds__(256, 4)
void wo_ffn_fused(const short* __restrict__ aggb, const short* __restrict__ wot,
                  const float* __restrict__ wo_b, short* __restrict__ hb,
                  const short* __restrict__ w1t, const float* __restrict__ b1,
                  const short* __restrict__ w2t, const float* __restrict__ b2,
                  const float* __restrict__ g1, const float* __restrict__ bl1,
                  const float* __restrict__ g2, const float* __restrict__ bl2,
                  const short* __restrict__ qkvw,  // packed W for layer l+1, or null
                  short* __restrict__ qb, unsigned char* __restrict__ kv8,
                  int M){
  __shared__ char ytile[8192];
  __shared__ char hidb[8192];
  __shared__ float rsum[4][32];
  __shared__ float rsq[4][32];
  const int tid = threadIdx.x;
  const int m0 = blockIdx.x * 32;
  const int lane = tid & 63, w = tid >> 6;     // w in 0..3 (col-wave)
  const int lrow = lane & 15, lgrp = lane >> 4;
  int rowA[2];
  #pragma unroll
  for (int r=0;r<2;r++){
    int rr = m0 + r*16 + lrow;
    rowA[r] = (rr < M) ? rr : (M-1);
  }

  // ---------- Phase A: Wo GEMM + residual + LN1 -> ytile ----------
  {
    const short8* W8 = (const short8*)wot;
    f32x4 acc[2][2];
    #pragma unroll
    for (int r=0;r<2;r++){ acc[r][0] = {0.f,0.f,0.f,0.f}; acc[r][1] = {0.f,0.f,0.f,0.f}; }
    #pragma unroll
    for (int kk = 0; kk < 4; kk++){
      const int koff = kk*32 + lgrp*8;
      short8 af[2], bfr[2];
      #pragma unroll
      for (int r = 0; r < 2; r++)
        af[r] = *(const short8*)(aggb + (size_t)rowA[r]*128 + koff);
      #pragma unroll
      for (int c = 0; c < 2; c++)
        bfr[c] = W8[(size_t)(w*2 + c)*256 + kk*64 + lane];
      #pragma unroll
      for (int r = 0; r < 2; r++)
        #pragma unroll
        for (int c = 0; c < 2; c++)
          acc[r][c] = __builtin_amdgcn_mfma_f32_16x16x32_bf16(af[r], bfr[c], acc[r][c], 0, 0, 0);
    }
    float o[2][2][4];
    float ps[2][4], pq[2][4];
    #pragma unroll
    for (int r=0;r<2;r++)
      #pragma unroll
      for (int v=0;v<4;v++){ ps[r][v]=0.f; pq[r][v]=0.f; }
    #pragma unroll
    for (int r = 0; r < 2; r++){
      #pragma unroll
      for (int c = 0; c < 2; c++){
        int col = w*32 + c*16 + lrow;
        float bv = wo_b[col];
        #pragma unroll
        for (int v = 0; v < 4; v++){
          int grow = m0 + r*16 + lgrp*4 + v;
          int gr = (grow < M) ? grow : (M-1);
          float oo = acc[r][c][v] + bv + bf2f(hb[(size_t)gr*128 + col]);
          o[r][c][v] = oo;
          ps[r][v] += oo;
          pq[r][v] += oo*oo;
        }
      }
    }
    #pragma unroll
    for (int r = 0; r < 2; r++)
      #pragma unroll
      for (int v = 0; v < 4; v++){
        #pragma unroll
        for (int off = 1; off < 16; off <<= 1){
          ps[r][v] += __shfl_xor(ps[r][v], off, 16);
          pq[r][v] += __shfl_xor(pq[r][v], off, 16);
        }
      }
    if (lrow == 0){
      #pragma unroll
      for (int r = 0; r < 2; r++)
        #pragma unroll
        for (int v = 0; v < 4; v++){
          int row = r*16 + lgrp*4 + v;
          rsum[w][row] = ps[r][v];
          rsq[w][row]  = pq[r][v];
        }
    }
    __syncthreads();                         // stats ready
    #pragma unroll
    for (int r = 0; r < 2; r++){
      float gv[2], bv2[2];
      #pragma unroll
      for (int c = 0; c < 2; c++){
        int col = w*32 + c*16 + lrow;
        gv[c] = g1[col]; bv2[c] = bl1[col];
      }
      #pragma unroll
      for (int v = 0; v < 4; v++){
        int row = r*16 + lgrp*4 + v;
        float s = (rsum[0][row]+rsum[1][row]) + (rsum[2][row]+rsum[3][row]);
        float q = (rsq[0][row]+rsq[1][row]) + (rsq[2][row]+rsq[3][row]);
        float mean = s * (1.f/128.f);
        float var  = q * (1.f/128.f) - mean*mean;
        float rstd = rsqrtf(var + 1e-5f);
        #pragma unroll
        for (int c = 0; c < 2; c++){
          int col = w*32 + c*16 + lrow;
          float y = (o[r][c][v] - mean)*rstd*gv[c] + bv2[c];
          int off = row*256 + col*2;
          *(short*)(ytile + (off ^ ((row & 7) << 4))) = f2bf(y);
        }
      }
    }
  }
  __syncthreads();                           // ytile ready

  // ---------- Phase B: FFN over 4 chunks of 128 hidden cols ----------
  const short8* W18 = (const short8*)w1t;
  const short8* W28 = (const short8*)w2t;
  f32x4 acc2[2][2];
  #pragma unroll
  for (int r=0;r<2;r++){ acc2[r][0] = {0.f,0.f,0.f,0.f}; acc2[r][1] = {0.f,0.f,0.f,0.f}; }
  #pragma unroll
  for (int chunk = 0; chunk < 4; chunk++){
    f32x4 acc1[2][2];
    #pragma unroll
    for (int r=0;r<2;r++){ acc1[r][0] = {0.f,0.f,0.f,0.f}; acc1[r][1] = {0.f,0.f,0.f,0.f}; }
    #pragma unroll
    for (int kk = 0; kk < 4; kk++){
      const int kbyt = kk*64 + lgrp*16;
      short8 af[2], bfr[2];
      #pragma unroll
      for (int r = 0; r < 2; r++){
        int row = r*16 + lrow;                 // local row 0..31
        af[r] = *(const short8*)(ytile + ((row*256 + kbyt) ^ ((row & 7) << 4)));
      }
      #pragma unroll
      for (int c = 0; c < 2; c++){
        int nb = chunk*8 + w*2 + c;            // n1/16
        bfr[c] = W18[(size_t)nb*256 + kk*64 + lane];
      }
      #pragma unroll
      for (int r = 0; r < 2; r++)
        #pragma unroll
        for (int c = 0; c < 2; c++)
          acc1[r][c] = __builtin_amdgcn_mfma_f32_16x16x32_bf16(af[r], bfr[c], acc1[r][c], 0, 0, 0);
    }
    __syncthreads();                     // prev chunk's FFN2 hidden reads done
    #pragma unroll
    for (int r = 0; r < 2; r++){
      #pragma unroll
      for (int c = 0; c < 2; c++){
        int lc = w*32 + c*16 + lrow;           // chunk-local col
        float bv = b1[chunk*128 + lc];
        #pragma unroll
        for (int v = 0; v < 4; v++){
          int row = r*16 + lgrp*4 + v;
          float g = gelu_f(acc1[r][c][v] + bv);
          int off = row*256 + lc*2;
          *(short*)(hidb + (off ^ ((row & 7) << 4))) = f2bf(g);
        }
      }
    }
    __syncthreads();                     // hidden ready
    #pragma unroll
    for (int kk2 = 0; kk2 < 4; kk2++){
      short8 ah[2], bh[2];
      #pragma unroll
      for (int r = 0; r < 2; r++){
        int row = r*16 + lrow;
        ah[r] = *(const short8*)(hidb + ((row*256 + kk2*64 + lgrp*16) ^ ((row & 7) << 4)));
      }
      #pragma unroll
      for (int c = 0; c < 2; c++){
        int nb = w*2 + c;                      // n2/16
        bh[c] = W28[(size_t)nb*1024 + chunk*256 + kk2*64 + lane];
      }
      #pragma unroll
      for (int r = 0; r < 2; r++)
        #pragma unroll
        for (int c = 0; c < 2; c++)
          acc2[r][c] = __builtin_amdgcn_mfma_f32_16x16x32_bf16(ah[r], bh[c], acc2[r][c], 0, 0, 0);
    }
  }

  // ---------- Phase C: LN2 (residual = ytile) -> hb AND ytile ----------
  {
    float o2[2][2][4];
    float ps[2][4], pq[2][4];
    #pragma unroll
    for (int r=0;r<2;r++)
      #pragma unroll
      for (int v=0;v<4;v++){ ps[r][v]=0.f; pq[r][v]=0.f; }
    #pragma unroll
    for (int r = 0; r < 2; r++){
      #pragma unroll
      for (int c = 0; c < 2; c++){
        int col = w*32 + c*16 + lrow;
        float bv = b2[col];
        #pragma unroll
        for (int v = 0; v < 4; v++){
          int row = r*16 + lgrp*4 + v;
          int off = row*256 + col*2;
          float res = bf2f(*(const short*)(ytile + (off ^ ((row & 7) << 4))));
          float oo = acc2[r][c][v] + bv + res;
          o2[r][c][v] = oo;
          ps[r][v] += oo;
          pq[r][v] += oo*oo;
        }
      }
    }
    #pragma unroll
    for (int r = 0; r < 2; r++)
      #pragma unroll
      for (int v = 0; v < 4; v++){
        #pragma unroll
        for (int off = 1; off < 16; off <<= 1){
          ps[r][v] += __shfl_xor(ps[r][v], off, 16);
          pq[r][v] += __shfl_xor(pq[r][v], off, 16);
        }
      }
    __syncthreads();                         // guard rsum reuse
    if (lrow == 0){
      #pragma unroll
      for (int r = 0; r < 2; r++)
        #pragma unroll
        for (int v = 0; v < 4; v++){
          int row = r*16 + lgrp*4 + v;
          rsum[w][row] = ps[r][v];
          rsq[w][row]  = pq[r][v];
        }
    }
    __syncthreads();
    #pragma unroll
    for (int r = 0; r < 2; r++){
      float gv[2], bv2[2];
      #pragma unroll
      for (int c = 0; c < 2; c++){
        int col = w*32 + c*16 + lrow;
        gv[c] = g2[col]; bv2[c] = bl2[col];
      }
      #pragma unroll
      for (int v = 0; v < 4; v++){
        int row = r*16 + lgrp*4 + v;
        int grow = m0 + row;
        float s = (rsum[0][row]+rsum[1][row]) + (rsum[2][row]+rsum[3][row]);
        float q = (rsq[0][row]+rsq[1][row]) + (rsq[2][row]+rsq[3][row]);
        float mean = s * (1.f/128.f);
        float var  = q * (1.f/128.f) - mean*mean;
        float rstd = rsqrtf(var + 1e-5f);
        #pragma unroll
        for (int c = 0; c < 2; c++){
          int col = w*32 + c*16 + lrow;
          float y = (o2[r][c][v] - mean)*rstd*gv[c] + bv2[c];
          if (grow < M) hb[(size_t)grow*128 + col] = f2bf(y);
          int off = row*256 + col*2;           // each thread re-writes the addrs it read
          *(short*)(ytile + (off ^ ((row & 7) << 4))) = f2bf(y);
        }
      }
    }
  }

  // ---------- Phase D: next-layer QKV from ytile (skipped on last layer) ----------
  if (qkvw != nullptr){
    __syncthreads();                         // ytile holds y2 for all rows
    #pragma unroll
    for (int m = 0; m < 3; m++){
      const short8* Wm = (const short8*)(qkvw + (size_t)m*16384);
      f32x4 accq[2][2];
      #pragma unroll
      for (int r=0;r<2;r++){ accq[r][0] = {0.f,0.f,0.f,0.f}; accq[r][1] = {0.f,0.f,0.f,0.f}; }
      #pragma unroll
      for (int kk = 0; kk < 4; kk++){
        const int kbyt = kk*64 + lgrp*16;
        short8 af[2], bfr[2];
        #pragma unroll
        for (int r = 0; r < 2; r++){
          int row = r*16 + lrow;
          af[r] = *(const short8*)(ytile + ((row*256 + kbyt) ^ ((row & 7) << 4)));
        }
        #pragma unroll
        for (int c = 0; c < 2; c++)
          bfr[c] = Wm[(size_t)(w*2 + c)*256 + kk*64 + lane];
        #pragma unroll
        for (int r = 0; r < 2; r++)
          #pragma unroll
          for (int c = 0; c < 2; c++)
            accq[r][c] = __builtin_amdgcn_mfma_f32_16x16x32_bf16(af[r], bfr[c], accq[r][c], 0, 0, 0);
      }
      #pragma unroll
      for (int r = 0; r < 2; r++){
        #pragma unroll
        for (int c = 0; c < 2; c++){
          int col = w*32 + c*16 + lrow;
          #pragma unroll
          for (int v = 0; v < 4; v++){
            int grow = m0 + r*16 + lgrp*4 + v;
            if (grow < M){
              float o = accq[r][c][v];
              if (m == 0) qb[(size_t)grow*128 + col] = f2bf(o);
              else        kv8[(size_t)grow*256 + (m-1)*128 + col] = f2fp8(o);
            }
          }
        }
      }
    }
  }
}

// ---------------- fused per-node attention: 4 chains, (256,8), fp8 K/V, CSR meta ------
__global__ __launch_bounds__(256, 8)
void attn_fused(const short* __restrict__ Qb, const unsigned char* __restrict__ KV8,
                const int2* __restrict__ em,
                const int* __restrict__ rowptr,
                const float* __restrict__ bb_l, short* __restrict__ aggb){
  const int lane = threadIdx.x & 63;
  const int i = (blockIdx.x << 2) + (threadIdx.x >> 6);
  if (i >= N_) return;
  const int hh = lane >> 3;
  const unsigned qw = ((const unsigned*)Qb)[(size_t)i*64 + lane];
  const float q0 = bflo(qw), q1 = bfhi(qw);
  const int p0 = __builtin_amdgcn_readfirstlane(rowptr[i]);
  const int p1 = __builtin_amdgcn_readfirstlane(rowptr[i+1]);
  constexpr float L2E = 1.442695040888963f;
  float2 outv = {0.f, 0.f};
  if (p0 < p1){
    float s[4]; float2 acc[4];
    #pragma unroll
    for (int c=0;c<4;c++){ s[c]=0.f; acc[c].x=0.f; acc[c].y=0.f; }
    int sj[4], sjN[4];
    float bb[4], ea[4], bbN[4], eaN[4];
    int kw[4], vw[4], kwN[4], vwN[4];

    auto ldmeta = [&](int gb, int* SJ, float* BB, float* EA){
      #pragma unroll
      for (int c = 0; c < 4; c++){
        int idx = gb + c; idx = (idx < p1) ? idx : (p1 - 1);
        int2 m = em[idx];
        unsigned u = (unsigned)__builtin_amdgcn_readfirstlane(m.x);
        SJ[c] = (int)(u & 0xFFFFu);
        BB[c] = bb_l[(u >> 16)*H_ + hh];
        EA[c] = __uint_as_float((unsigned)__builtin_amdgcn_readfirstlane(m.y));
      }
    };

    ldmeta(p0, sj, bb, ea);
    #pragma unroll
    for (int c = 0; c < 4; c++){
      kw[c] = *(const unsigned short*)(KV8 + (size_t)sj[c]*256 + lane*2);
      vw[c] = *(const unsigned short*)(KV8 + (size_t)sj[c]*256 + 128 + lane*2);
    }
    ldmeta(p0 + 4, sjN, bbN, eaN);

    for (int base = p0; base < p1; base += 4){
      #pragma unroll
      for (int c = 0; c < 4; c++){
        kwN[c] = *(const unsigned short*)(KV8 + (size_t)sjN[c]*256 + lane*2);
        vwN[c] = *(const unsigned short*)(KV8 + (size_t)sjN[c]*256 + 128 + lane*2);
      }
      int sj2[4]; float bb2[4], ea2[4];
      ldmeta(base + 8, sj2, bb2, ea2);
      #pragma unroll
      for (int c = 0; c < 4; c++){
        f32x2 kf = __builtin_amdgcn_cvt_pk_f32_fp8(kw[c], false);
        float dot = q0*kf[0] + q1*kf[1];
        dot += __shfl_xor(dot, 1, 8);
        dot += __shfl_xor(dot, 2, 8);
        dot += __shfl_xor(dot, 4, 8);
        float logit = (dot*0.25f + bb[c]) * ea[c];
        logit = fminf(logit, 60.f);
        if (base + c >= p1) logit = -1.0e30f;   // tail slot -> weight 0
        float wgt = exp2f(logit * L2E);
        f32x2 vf = __builtin_amdgcn_cvt_pk_f32_fp8(vw[c], false);
        s[c]     += wgt;
        acc[c].x += wgt*vf[0];
        acc[c].y += wgt*vf[1];
      }
      #pragma unroll
      for (int c = 0; c < 4; c++){
        kw[c]=kwN[c]; vw[c]=vwN[c];
        sj[c]=sjN[c]; bb[c]=bbN[c]; ea[c]=eaN[c];
        sjN[c]=sj2[c]; bbN[c]=bb2[c]; eaN[c]=ea2[c];
      }
    }
    float S = (s[0]+s[1]) + (s[2]+s[3]);
    float Ax = (acc[0].x+acc[1].x) + (acc[2].x+acc[3].x);
    float Ay = (acc[0].y+acc[1].y) + (acc[2].y+acc[3].y);
    float inv = 1.0f / (S + 1e-16f);
    outv.x = Ax * inv;
    outv.y = Ay * inv;
  }
  unsigned lo = (unsigned)(unsigned short)f2bf(outv.x);
  unsigned hi = (unsigned)(unsigned short)f2bf(outv.y);
  ((unsigned*)aggb)[(size_t)i*64 + lane] = lo | (hi << 16);
}

extern "C" void kernel_launch(void* const* d_in, const int* in_sizes, int n_in,
                              void* d_out, int out_size, void* d_ws, size_t ws_size,
                              hipStream_t stream) {
  const float* x         = (const float*)d_in[0];
  const int*   edge_index= (const int*)  d_in[1];
  const float* edge_attr = (const float*)d_in[2];
  const int*   band_ids  = (const int*)  d_in[3];
  const int*   stage_ids = (const int*)  d_in[4];
  const float* stage_emb = (const float*)d_in[5];
  const float* in_w      = (const float*)d_in[6];
  const float* in_b      = (const float*)d_in[7];
  const float* Wq        = (const float*)d_in[8];
  const float* Wk        = (const float*)d_in[9];
  const float* Wv        = (const float*)d_in[10];
  const float* Wo        = (const float*)d_in[11];
  const float* Wo_b      = (const float*)d_in[12];
  const float* band_bias = (const float*)d_in[13];
  const float* ln1_g     = (const float*)d_in[14];
  const float* ln1_b     = (const float*)d_in[15];
  const float* ffn_w1    = (const float*)d_in[16];
  const float* ffn_b1    = (const float*)d_in[17];
  const float* ffn_w2    = (const float*)d_in[18];
  const float* ffn_b2    = (const float*)d_in[19];
  const float* ln2_g     = (const float*)d_in[20];
  const float* ln2_b     = (const float*)d_in[21];
  const float* out_w     = (const float*)d_in[22];
  const float* out_b     = (const float*)d_in[23];
  float* out = (float*)d_out;

  const size_t ND = (size_t)N_*D_;           // 6.4M
  float* ws  = (float*)d_ws;
  short* hb   = (short*)ws;                  // bf16 N x 128 (ONLY hidden state)
  short* aggb = (short*)(ws + ND);           // bf16 N x 128
  short* qb   = (short*)(ws + 2*ND);         // bf16 Q N x 128
  unsigned char* kv8 = (unsigned char*)(ws + 2*ND + ND/2);  // fp8 KV [N][256B]
  short* wbuf = (short*)(ws + 3*ND + ND/2);  // packed bf16 weights: 802816 shorts
  short* wqkvt = wbuf;
  short* wot   = wbuf + 196608;
  short* w1t   = wbuf + 262144;
  short* w2t   = wbuf + 524288;
  short* owt   = wbuf + 786432;
  int*  ibase = (int*)(ws + 3*ND + ND/2 + 401408);
  int*  deg   = ibase;                       // N
  int*  fill  = ibase + N_;                  // N
  int*  rowptr= ibase + 2*N_;                // N+1
  int*  eord  = ibase + 3*N_ + 1;            // E
  int*  bsum  = ibase + 3*N_ + 1 + E_;       // 64
  int*  pk    = ibase + 3*N_ + 1 + E_ + 64;  // E
  int2* em    = (int2*)(ibase + 3*N_ + 1 + 2*E_ + 64);  // E int2

  const int* srcA = edge_index;
  const int* dstA = edge_index + E_;

  hipMemsetAsync(deg, 0, 2ull*N_*sizeof(int), stream);

  conv_weights<<<3136, 256, 0, stream>>>(Wq, Wk, Wv, Wo, ffn_w1, ffn_w2, out_w,
                                         wqkvt, wot, w1t, w2t, owt);
  input_proj<<<N_/2, 256, 0, stream>>>(x, in_w, in_b, stage_emb, stage_ids, hb);

  k_deg   <<<(E_+255)/256, 256, 0, stream>>>(dstA, srcA, band_ids, deg, pk);
  k_scan1 <<<49, 1024, 0, stream>>>(deg, rowptr, bsum);
  k_scan2 <<<1, 64, 0, stream>>>(bsum, 49);
  k_scan3 <<<(N_+255)/256, 256, 0, stream>>>(rowptr, bsum);
  k_scatter<<<(E_+255)/256, 256, 0, stream>>>(dstA, rowptr, fill, eord);
  k_sortseg<<<(N_+255)/256, 256, 0, stream>>>(rowptr, eord);
  k_emeta <<<(E_+255)/256, 256, 0, stream>>>(eord, pk, edge_attr, em);

  const int GB  = (N_ + 127) / 128;          // 391
  const int GB3 = (N_ + 31) / 32;            // 1563
  const int AB  = (N_ + 3) / 4;              // 12500

  // layer-0 QKV (standalone); layers 1..3 QKV are produced by Phase D of the fused tail
  gemm128_direct<4><<<dim3(GB,3), 512, 0, stream>>>(
      hb, wqkvt, nullptr, nullptr, qb, kv8, N_, 16384L);

  for (int l = 0; l < L_; l++){
    attn_fused<<<AB, 256, 0, stream>>>(qb, kv8, em, rowptr,
                                       band_bias + l*NB_*H_, aggb);

    const short* qkvw_next = (l < L_-1) ? (wqkvt + (size_t)(l+1)*3*16384) : nullptr;
    wo_ffn_fused<<<GB3, 256, 0, stream>>>(
        aggb, wot + (size_t)l*16384, Wo_b + l*D_, hb,
        w1t + (size_t)l*65536, ffn_b1 + l*DFF_,
        w2t + (size_t)l*65536, ffn_b2 + l*D_,
        ln1_g + l*D_, ln1_b + l*D_, ln2_g + l*D_, ln2_b + l*D_,
        qkvw_next, qb, kv8, N_);
  }

  gemm128_direct<3><<<GB, 512, 0, stream>>>(
      hb, owt, out_b, out, nullptr, nullptr, N_, 0L);
}